// Round 9
// baseline (139.407 us; speedup 1.0000x reference)
//
#include <hip/hip_runtime.h>

// BPMLL loss, B=16384 rows, L=1024 cols, f32 in, scalar f32 out.
// Per row: pos = sum y*exp(-c); neg = sum (1-y)*exp(c);
// loss = pos*neg/(sum_y*(L-sum_y)); out = mean over rows.
//
// Ledger: R1/R2/R4 ~43us (3.1 TB/s). R6 nt+persistent+dbuf ~37us (3.7 TB/s).
// R7 (2x waves/CU) neutral. R8 (2x burst length) neutral. Read rate pinned
// at ~3.7 TB/s across six structures; fabric proven capable of 6.5 TB/s
// writes (harness fills) and 4.9 TB/s reads (m146) — but no source-level
// lever moved it. R9: fuse out the 2nd dispatch — per-block atomicAdd to
// out[0] (512 device-scope f32 atomics), out zeroed via 4-byte memset node.

#define NROWS 16384
#define NCOLS 1024
#define WPB 4
#define NBLOCKS 512                        // 2 blocks/CU, co-resident
#define ROWS_PER_WAVE (NROWS / (NBLOCKS * WPB))  // 8

typedef float vf4 __attribute__((ext_vector_type(4)));
typedef int vi4 __attribute__((ext_vector_type(4)));

__device__ __forceinline__ void elem(float cv, int yv,
                                     float& pos, float& neg, float& cnt) {
    float t = __expf(yv ? -cv : cv);   // one transcendental per element
    pos += yv ? t : 0.f;
    neg += yv ? 0.f : t;
    cnt += (float)yv;
}

__device__ __forceinline__ void consume4(const vf4& cv, const vi4& yv,
                                         float& pos, float& neg, float& cnt) {
    elem(cv.x, yv.x, pos, neg, cnt);
    elem(cv.y, yv.y, pos, neg, cnt);
    elem(cv.z, yv.z, pos, neg, cnt);
    elem(cv.w, yv.w, pos, neg, cnt);
}

__device__ __forceinline__ float row_finish(float pos, float neg, float cnt) {
#pragma unroll
    for (int off = 1; off < 64; off <<= 1) {
        pos += __shfl_xor(pos, off);
        neg += __shfl_xor(neg, off);
        cnt += __shfl_xor(cnt, off);
    }
    return (pos * neg) / (cnt * ((float)NCOLS - cnt));  // BIAS=(1,1)
}

__global__ __launch_bounds__(256, 2) void bpmll_rows_kernel(
    const float* __restrict__ c, const int* __restrict__ y,
    float* __restrict__ out) {
    const int wave = threadIdx.x >> 6;
    const int lane = threadIdx.x & 63;
    const int gw = blockIdx.x * WPB + wave;        // 0..2047
    const int row0 = gw * ROWS_PER_WAVE;           // 8 contiguous rows/wave

    const vf4* __restrict__ cp = (const vf4*)(c + (size_t)row0 * NCOLS);
    const vi4* __restrict__ yp = (const vi4*)(y + (size_t)row0 * NCOLS);
    // row stride = 256 vf4 / vi4

    vf4 cbuf[2][4];
    vi4 ybuf[2][4];

    // Prime the pipeline: row 0 into buffer 0 (nontemporal).
#pragma unroll
    for (int i = 0; i < 4; ++i)
        cbuf[0][i] = __builtin_nontemporal_load(&cp[lane + 64 * i]);
#pragma unroll
    for (int i = 0; i < 4; ++i)
        ybuf[0][i] = __builtin_nontemporal_load(&yp[lane + 64 * i]);

    float wave_loss = 0.f;
#pragma unroll
    for (int r = 0; r < ROWS_PER_WAVE; ++r) {
        const int cur = r & 1, nxt = cur ^ 1;
        if (r < ROWS_PER_WAVE - 1) {  // prefetch next row while consuming
            const vf4* cn = cp + (size_t)(r + 1) * (NCOLS / 4);
            const vi4* yn = yp + (size_t)(r + 1) * (NCOLS / 4);
#pragma unroll
            for (int i = 0; i < 4; ++i)
                cbuf[nxt][i] = __builtin_nontemporal_load(&cn[lane + 64 * i]);
#pragma unroll
            for (int i = 0; i < 4; ++i)
                ybuf[nxt][i] = __builtin_nontemporal_load(&yn[lane + 64 * i]);
        }
        float pos = 0.f, neg = 0.f, cnt = 0.f;
#pragma unroll
        for (int i = 0; i < 4; ++i)
            consume4(cbuf[cur][i], ybuf[cur][i], pos, neg, cnt);
        wave_loss += row_finish(pos, neg, cnt);
    }

    __shared__ float acc[WPB];
    if (lane == 0) acc[wave] = wave_loss;
    __syncthreads();
    if (threadIdx.x == 0) {
        // One device-scope atomic per block (512 total) -> fused final sum.
        atomicAdd(out, (acc[0] + acc[1] + acc[2] + acc[3]) *
                           (1.0f / (float)NROWS));
    }
}

extern "C" void kernel_launch(void* const* d_in, const int* in_sizes, int n_in,
                              void* d_out, int out_size, void* d_ws, size_t ws_size,
                              hipStream_t stream) {
    const float* c = (const float*)d_in[0];
    const int* y = (const int*)d_in[1];
    float* out = (float*)d_out;

    // d_out is poisoned 0xAA before every call; zero it for the atomics.
    hipMemsetAsync(out, 0, sizeof(float), stream);
    bpmll_rows_kernel<<<NBLOCKS, 256, 0, stream>>>(c, y, out);
}

// Round 10
// 137.839 us; speedup vs baseline: 1.0114x; 1.0114x over previous
//
#include <hip/hip_runtime.h>

// BPMLL loss, B=16384 rows, L=1024 cols, f32 in, scalar f32 out.
// Per row: pos = sum y*exp(-c); neg = sum (1-y)*exp(c);
// loss = pos*neg/(sum_y*(L-sum_y)); out = mean over rows.
//
// FINAL (R6 config, session best: 136.7us total, rows kernel ~37us).
// Ledger: R1/R2/R4 ~43us (3.1 TB/s). R6 nt+persistent+register-dbuf ~37us
// (3.7 TB/s pure read — at/above every measured read ceiling in the corpus:
// m13 copy read-direction 3.15 TB/s, m146 R+W 4.89). Falsified levers:
// wave count (R1 vs R2), per-wave MLP (R4), waves/CU 8->16 (R7), burst
// length 4KB->8KB (R8), dispatch fusion via atomics (R9). 128 MiB read is
// irreducible; 134MB / 3.7TB/s = 36us = where we are. Memory-bound roofline.

#define NROWS 16384
#define NCOLS 1024
#define WPB 4
#define NBLOCKS 512                        // 2 blocks/CU, co-resident
#define ROWS_PER_WAVE (NROWS / (NBLOCKS * WPB))  // 8

typedef float vf4 __attribute__((ext_vector_type(4)));
typedef int vi4 __attribute__((ext_vector_type(4)));

__device__ __forceinline__ void elem(float cv, int yv,
                                     float& pos, float& neg, float& cnt) {
    float t = __expf(yv ? -cv : cv);   // one transcendental per element
    pos += yv ? t : 0.f;
    neg += yv ? 0.f : t;
    cnt += (float)yv;
}

__device__ __forceinline__ void consume4(const vf4& cv, const vi4& yv,
                                         float& pos, float& neg, float& cnt) {
    elem(cv.x, yv.x, pos, neg, cnt);
    elem(cv.y, yv.y, pos, neg, cnt);
    elem(cv.z, yv.z, pos, neg, cnt);
    elem(cv.w, yv.w, pos, neg, cnt);
}

__device__ __forceinline__ float row_finish(float pos, float neg, float cnt) {
#pragma unroll
    for (int off = 1; off < 64; off <<= 1) {
        pos += __shfl_xor(pos, off);
        neg += __shfl_xor(neg, off);
        cnt += __shfl_xor(cnt, off);
    }
    return (pos * neg) / (cnt * ((float)NCOLS - cnt));  // BIAS=(1,1)
}

__global__ __launch_bounds__(256, 2) void bpmll_rows_kernel(
    const float* __restrict__ c, const int* __restrict__ y,
    float* __restrict__ partials) {
    const int wave = threadIdx.x >> 6;
    const int lane = threadIdx.x & 63;
    const int gw = blockIdx.x * WPB + wave;        // 0..2047
    const int row0 = gw * ROWS_PER_WAVE;           // 8 contiguous rows/wave

    const vf4* __restrict__ cp = (const vf4*)(c + (size_t)row0 * NCOLS);
    const vi4* __restrict__ yp = (const vi4*)(y + (size_t)row0 * NCOLS);
    // row stride = 256 vf4 / vi4

    vf4 cbuf[2][4];
    vi4 ybuf[2][4];

    // Prime the pipeline: row 0 into buffer 0 (nontemporal).
#pragma unroll
    for (int i = 0; i < 4; ++i)
        cbuf[0][i] = __builtin_nontemporal_load(&cp[lane + 64 * i]);
#pragma unroll
    for (int i = 0; i < 4; ++i)
        ybuf[0][i] = __builtin_nontemporal_load(&yp[lane + 64 * i]);

    float wave_loss = 0.f;
#pragma unroll
    for (int r = 0; r < ROWS_PER_WAVE; ++r) {
        const int cur = r & 1, nxt = cur ^ 1;
        if (r < ROWS_PER_WAVE - 1) {  // prefetch next row while consuming
            const vf4* cn = cp + (size_t)(r + 1) * (NCOLS / 4);
            const vi4* yn = yp + (size_t)(r + 1) * (NCOLS / 4);
#pragma unroll
            for (int i = 0; i < 4; ++i)
                cbuf[nxt][i] = __builtin_nontemporal_load(&cn[lane + 64 * i]);
#pragma unroll
            for (int i = 0; i < 4; ++i)
                ybuf[nxt][i] = __builtin_nontemporal_load(&yn[lane + 64 * i]);
        }
        float pos = 0.f, neg = 0.f, cnt = 0.f;
#pragma unroll
        for (int i = 0; i < 4; ++i)
            consume4(cbuf[cur][i], ybuf[cur][i], pos, neg, cnt);
        wave_loss += row_finish(pos, neg, cnt);
    }

    __shared__ float acc[WPB];
    if (lane == 0) acc[wave] = wave_loss;
    __syncthreads();
    if (threadIdx.x == 0) {
        partials[blockIdx.x] =
            (acc[0] + acc[1] + acc[2] + acc[3]) * (1.0f / (float)NROWS);
    }
}

__global__ __launch_bounds__(256) void bpmll_reduce_kernel(
    const float* __restrict__ partials, float* __restrict__ out) {
    // 512 partials, 256 threads -> two floats per thread.
    float s = partials[threadIdx.x] + partials[threadIdx.x + 256];
#pragma unroll
    for (int off = 1; off < 64; off <<= 1) s += __shfl_xor(s, off);

    __shared__ float smem[4];
    const int lane = threadIdx.x & 63;
    const int wave = threadIdx.x >> 6;
    if (lane == 0) smem[wave] = s;
    __syncthreads();
    if (threadIdx.x == 0) out[0] = smem[0] + smem[1] + smem[2] + smem[3];
}

extern "C" void kernel_launch(void* const* d_in, const int* in_sizes, int n_in,
                              void* d_out, int out_size, void* d_ws, size_t ws_size,
                              hipStream_t stream) {
    const float* c = (const float*)d_in[0];
    const int* y = (const int*)d_in[1];
    float* partials = (float*)d_ws;   // NBLOCKS floats = 2 KiB scratch
    float* out = (float*)d_out;

    bpmll_rows_kernel<<<NBLOCKS, 256, 0, stream>>>(c, y, partials);
    bpmll_reduce_kernel<<<1, 256, 0, stream>>>(partials, out);
}